// Round 6
// baseline (82.008 us; speedup 1.0000x reference)
//
#include <hip/hip_runtime.h>
#include <hip/hip_cooperative_groups.h>
#include <math.h>

namespace cg = cooperative_groups;

#define B_SZ   32
#define T_LEN  500
#define VOCAB  8192

// One cooperative kernel: 512 blocks x 512 threads.
// Block b computes cross[i][j0] and cross[i][j1] for p0=2b -> i=p0>>5,
// j0=p0&31, j1=j0+1 (i identical for both pairs). One Y-load, two gathers
// per thread. Then grid.sync(); block 0 finalizes.
__global__ void __launch_bounds__(512)
infonce_coop_kernel(const float* __restrict__ x,
                    const int*   __restrict__ Y,
                    const float* __restrict__ B_buf,
                    float*       __restrict__ out,
                    float*       __restrict__ cross) {
    const int b   = blockIdx.x;        // 0..511
    const int tid = threadIdx.x;
    const int p0  = b * 2;
    const int i   = p0 >> 5;           // target sample (same for both pairs)
    const int j0  = p0 & 31;           // logits samples j0, j0+1
    const int j1  = j0 + 1;

    // ---- gather phase ----
    float acc0 = 0.0f, acc1 = 0.0f;
    if (tid < T_LEN) {
        const int y = Y[i * T_LEN + tid];             // one index load
        const size_t off = (size_t)tid * VOCAB + (size_t)y;
        const float v0 = x[(size_t)j0 * T_LEN * VOCAB + off];  // independent
        const float v1 = x[(size_t)j1 * T_LEN * VOCAB + off];  // independent
        acc0 = fminf(fmaxf(v0, -30.0f), 30.0f);
        acc1 = fminf(fmaxf(v1, -30.0f), 30.0f);
    }

    #pragma unroll
    for (int off = 32; off > 0; off >>= 1) {
        acc0 += __shfl_down(acc0, off, 64);
        acc1 += __shfl_down(acc1, off, 64);
    }

    __shared__ float ws0[8], ws1[8];
    if ((tid & 63) == 0) { ws0[tid >> 6] = acc0; ws1[tid >> 6] = acc1; }
    __syncthreads();
    if (tid == 0) {
        float s0 = 0.0f, s1 = 0.0f;
        #pragma unroll
        for (int w = 0; w < 8; ++w) { s0 += ws0[w]; s1 += ws1[w]; }
        cross[i * B_SZ + j0] = s0;
        cross[i * B_SZ + j1] = s1;
    }

    // ---- grid-wide barrier (includes agent-scope memory fence) ----
    cg::this_grid().sync();

    // ---- finalize: block 0, first wave only; register-light (L2 reads) ----
    if (b == 0 && tid < 64) {
        const int lane = tid;
        const float b0 = B_buf[0];
        float lt = 0.0f;
        if (lane < B_SZ) {
            float m = -INFINITY;
            #pragma unroll 4
            for (int jj = 0; jj < B_SZ; ++jj)
                m = fmaxf(m, cross[lane * B_SZ + jj]);
            float s = 0.0f;
            #pragma unroll 4
            for (int jj = 0; jj < B_SZ; ++jj)
                s += expf(cross[lane * B_SZ + jj] - m);
            const float lse = m + logf(s);
            const float hi  = fmaxf(lse, b0);
            const float lo  = fminf(lse, b0);
            const float den = hi + log1pf(expf(lo - hi));
            lt = cross[lane * B_SZ + lane] - den;
        }
        float s_lt = (lane < B_SZ) ? lt       : 0.0f;
        float s_ex = (lane < B_SZ) ? expf(lt) : 0.0f;
        #pragma unroll
        for (int off = 16; off > 0; off >>= 1) {
            s_lt += __shfl_down(s_lt, off, 64);
            s_ex += __shfl_down(s_ex, off, 64);
        }
        if (lane == 0) {
            out[0] = -s_lt / ((float)B_SZ * (float)T_LEN);  // loss
            out[1] = s_ex * (float)T_LEN;                   // correct
        }
    }
}

extern "C" void kernel_launch(void* const* d_in, const int* in_sizes, int n_in,
                              void* d_out, int out_size, void* d_ws, size_t ws_size,
                              hipStream_t stream) {
    const float* x     = (const float*)d_in[0];   // [32, 500, 8192] f32
    const int*   Y     = (const int*)  d_in[1];   // [32, 500]
    const float* B_buf = (const float*)d_in[2];   // [R+1]
    float* out   = (float*)d_out;                 // [loss, correct]
    float* cross = (float*)d_ws;                  // 32*32 f32 scratch

    void* args[] = { (void*)&x, (void*)&Y, (void*)&B_buf, (void*)&out, (void*)&cross };
    hipLaunchCooperativeKernel((const void*)infonce_coop_kernel,
                               dim3(512), dim3(512), args, 0, stream);
}